// Round 4
// baseline (269.587 us; speedup 1.0000x reference)
//
#include <hip/hip_runtime.h>
#include <math.h>

// Problem constants (match reference)
#define BATCH 65536
#define NCLS  10
#define NBLK  2048              // 2048 blocks = exactly 8.0 rounds of 256 CUs
                                // each block: 4 waves x 8 KL rows = 32 KL rows
                                //             + 32 CE rows (lanes 0-7 of each wave)

// ws layout: ws[b*3+0]=ce, +1=H, +2=kl  -> 2048*3 doubles = 49 KiB

// Native clang vector type (vector loads; NT hint removed this round).
typedef float vf4 __attribute__((ext_vector_type(4)));

// R10 evidence chain:
//  * R9 ((256,4) + sched_barrier): the pinned 32-load batch needs >=128 data
//    regs; at budget 128 it SPILLED (WRITE_SIZE 68KB->8.4MB) and regressed
//    24%. Occupancy test confounded.
//  * Concurrency arithmetic: AGPR-backed batch = 256 KB outstanding/CU vs
//    ~9 KB Little's-law need. 25x margin in every config; all non-spill
//    configs sit at 5.73 TB/s consumed. -> throughput cap, not concurrency.
//  * R10 targets the last 9% to the 6.29 TB/s copy ceiling:
//    (a) drop the nt hint (never A/B'd; nt changes L2/LLC alloc path,
//        zero benefit for read-once data),
//    (b) even grid: fold CE into KL blocks -> 2048 blocks = 8.0 exact
//        rounds, killing the 0.25-round tail (~3%).
//    Revert to (256,2): known non-spilling.
//  * If flat at 47-48 us: cap confirmed on every axis -> ROOFLINE next.
//
// Numerics: max-subtraction omitted (N(0,1)-derived logits, extreme ~40,
// expf fine in fp32). R1-R9 absmax 0.0 vs 6e-2 threshold.

__global__ __launch_bounds__(256, 2) void crit_main(
    const float* __restrict__ mean_t,      const float* __restrict__ mean_s,
    const float* __restrict__ log_std_t,   const float* __restrict__ log_std_s,
    const float* __restrict__ y_zt,        const float* __restrict__ s_zt,
    const float* __restrict__ eps_prior_t, const float* __restrict__ eps_prior_s,
    const float* __restrict__ eps_t,       const float* __restrict__ eps_s,
    const int*   __restrict__ target,
    double*      __restrict__ ws_partial)
{
    const int tid = threadIdx.x;
    const int wid = tid >> 6;
    const int lane = tid & 63;

    // ---------------- KL phase: 16 lanes per row, 8 rows per wave ----------------
    const int sub  = lane & 15;          // lane within 16-lane group
    const int grp  = (lane >> 4) & 3;    // 4 groups = 4 rows per group-iter
    const int gwave = blockIdx.x * 4 + wid;
    const int rowbase = gwave * 8;       // 8 rows per wave (2 groups x 4)

    const vf4* MT = (const vf4*)mean_t;
    const vf4* LT = (const vf4*)log_std_t;
    const vf4* ET = (const vf4*)eps_t;
    const vf4* PT = (const vf4*)eps_prior_t;
    const vf4* MS = (const vf4*)mean_s;
    const vf4* LS = (const vf4*)log_std_s;
    const vf4* ES = (const vf4*)eps_s;
    const vf4* PS = (const vf4*)eps_prior_s;

    // vf4 indices for both row-groups
    int i0[2], i1[2];
    #pragma unroll
    for (int k = 0; k < 2; ++k) {
        const int row = rowbase + k * 4 + grp;
        i0[k] = row * 32 + sub;          // floats [sub*4 .. ) of the row
        i1[k] = i0[k] + 16;              // second half of the row
    }

    // ---- issue the stream loads (plain loads; nt hint removed) ----
    vf4 mt[2][2], lt[2][2], et[2][2], pt[2][2];
    vf4 ms[2][2], ls[2][2], es[2][2], ps[2][2];
    #pragma unroll
    for (int k = 0; k < 2; ++k) {
        mt[k][0] = MT[i0[k]];  mt[k][1] = MT[i1[k]];
        lt[k][0] = LT[i0[k]];  lt[k][1] = LT[i1[k]];
        et[k][0] = ET[i0[k]];  et[k][1] = ET[i1[k]];
        pt[k][0] = PT[i0[k]];  pt[k][1] = PT[i1[k]];
        ms[k][0] = MS[i0[k]];  ms[k][1] = MS[i1[k]];
        ls[k][0] = LS[i0[k]];  ls[k][1] = LS[i1[k]];
        es[k][0] = ES[i0[k]];  es[k][1] = ES[i1[k]];
        ps[k][0] = PS[i0[k]];  ps[k][1] = PS[i1[k]];
    }
    // Scheduler fence: math may not be hoisted into the load clause.
    __builtin_amdgcn_sched_barrier(0);

    // ---- elementwise collapse: 6 partials per group ----
    // red[k]: 0=Ze_t 1=Zp_t 2=S_t 3=Ze_s 4=Zp_s 5=S_s
    float red[2][6];
    #pragma unroll
    for (int k = 0; k < 2; ++k) {
        #pragma unroll
        for (int j = 0; j < 6; ++j) red[k][j] = 0.0f;
        #pragma unroll
        for (int h = 0; h < 2; ++h) {
            #pragma unroll
            for (int c = 0; c < 4; ++c) {
                const float enc_t = fmaf(__expf(0.5f * lt[k][h][c]), et[k][h][c], mt[k][h][c]);
                const float enc_s = fmaf(__expf(0.5f * ls[k][h][c]), es[k][h][c], ms[k][h][c]);
                const float xt = __expf(enc_t);
                const float xs = __expf(enc_s);
                red[k][0] += xt;
                red[k][1] += __expf(pt[k][h][c]);
                red[k][2] += xt * (enc_t - pt[k][h][c]);
                red[k][3] += xs;
                red[k][4] += __expf(ps[k][h][c]);
                red[k][5] += xs * (enc_s - ps[k][h][c]);
            }
        }
    }

    // ---- joint butterfly: 4 levels x 12 values; each 16-lane group
    //      reduces its own row in the same instructions ----
    #pragma unroll
    for (int m = 8; m >= 1; m >>= 1) {
        #pragma unroll
        for (int k = 0; k < 2; ++k) {
            #pragma unroll
            for (int j = 0; j < 6; ++j) red[k][j] += __shfl_xor(red[k][j], m, 64);
        }
    }

    float kl = 0.0f;
    #pragma unroll
    for (int k = 0; k < 2; ++k) {
        const float rt = 1.0f / red[k][0];
        const float rs = 1.0f / red[k][3];
        kl += red[k][2] * rt + __logf(red[k][1] * rt)
            + red[k][5] * rs + __logf(red[k][4] * rs);
    }
    // Cross-group reduce (xor 16/32 only combine ACROSS the 4 groups,
    // each of which holds a group-uniform kl -> each row counted once).
    kl += __shfl_xor(kl, 16, 64);
    kl += __shfl_xor(kl, 32, 64);

    // ---------------- CE phase: lanes 0-7 of each wave take one row ----------------
    // Block covers CE rows [blockIdx.x*32, +32): wave wid, lane l<8 -> row +wid*8+l.
    double ce_d = 0.0, H_d = 0.0;
    if (lane < 8) {
        const int r = blockIdx.x * 32 + wid * 8 + lane;
        const float* yr = y_zt + (size_t)r * NCLS;
        const float2 y0 = *(const float2*)(yr + 0);
        const float2 y1 = *(const float2*)(yr + 2);
        const float2 y2 = *(const float2*)(yr + 4);
        const float2 y3 = *(const float2*)(yr + 6);
        const float2 y4 = *(const float2*)(yr + 8);
        const float2 s2 = *(const float2*)(s_zt + (size_t)r * 2);
        const int    t  = target[r];

        float yt = y0.x;
        yt = (t == 1) ? y0.y : yt;
        yt = (t == 2) ? y1.x : yt;
        yt = (t == 3) ? y1.y : yt;
        yt = (t == 4) ? y2.x : yt;
        yt = (t == 5) ? y2.y : yt;
        yt = (t == 6) ? y3.x : yt;
        yt = (t == 7) ? y3.y : yt;
        yt = (t == 8) ? y4.x : yt;
        yt = (t == 9) ? y4.y : yt;

        const float Z = (__expf(y0.x) + __expf(y0.y))
                      + (__expf(y1.x) + __expf(y1.y))
                      + (__expf(y2.x) + __expf(y2.y))
                      + (__expf(y3.x) + __expf(y3.y))
                      + (__expf(y4.x) + __expf(y4.y));
        ce_d = (double)(__logf(Z) - yt);

        const float za = __expf(s2.x), zb = __expf(s2.y);
        const float Zs = za + zb;
        const float lses = __logf(Zs);
        H_d = (double)(-((za / Zs) * (s2.x - lses) + (zb / Zs) * (s2.y - lses)));
    }
    // 3-level butterfly sums lanes 0-7 into lane 0 (xor m<=4 stays within
    // each 8-lane group; lanes >=8 hold zeros and sum among themselves).
    #pragma unroll
    for (int m = 4; m >= 1; m >>= 1) {
        ce_d += __shfl_xor(ce_d, m, 64);
        H_d  += __shfl_xor(H_d,  m, 64);
    }

    // ---------------- block epilogue: 1 barrier, 3 doubles out ----------------
    __shared__ double sred[4][3];
    if (lane == 0) {
        sred[wid][0] = ce_d;
        sred[wid][1] = H_d;
        sred[wid][2] = (double)kl;
    }
    __syncthreads();
    if (tid == 0) {
        ws_partial[blockIdx.x * 3 + 0] = sred[0][0] + sred[1][0] + sred[2][0] + sred[3][0];
        ws_partial[blockIdx.x * 3 + 1] = sred[0][1] + sred[1][1] + sred[2][1] + sred[3][1];
        ws_partial[blockIdx.x * 3 + 2] = sred[0][2] + sred[1][2] + sred[2][2] + sred[3][2];
    }
}

__global__ __launch_bounds__(256) void crit_reduce(
    const double* __restrict__ ws_partial,
    const int*    __restrict__ step_ptr,
    float*        __restrict__ out)
{
    const int tid = threadIdx.x;
    double c = 0.0, h = 0.0, k = 0.0;
    for (int i = tid; i < NBLK; i += 256) {
        c += ws_partial[3 * i + 0];
        h += ws_partial[3 * i + 1];
        k += ws_partial[3 * i + 2];
    }
    __shared__ double sc[256], sh_[256], sk[256];
    sc[tid] = c; sh_[tid] = h; sk[tid] = k;
    __syncthreads();
    for (int s = 128; s > 0; s >>= 1) {
        if (tid < s) { sc[tid] += sc[tid + s]; sh_[tid] += sh_[tid + s]; sk[tid] += sk[tid + s]; }
        __syncthreads();
    }
    if (tid == 0) {
        double frac  = (double)step_ptr[0] / 1000.0;   // STEP_SIZE
        double lam_e  = 0.1   * exp2(frac);            // LAMBDA_E * 2^frac
        double lam_od = 0.036 * exp2(frac);            // LAMBDA_OD * 2^frac
        out[0] = (float)((sc[0] + lam_e * sh_[0] + lam_od * sk[0]) / (double)BATCH);
    }
}

extern "C" void kernel_launch(void* const* d_in, const int* in_sizes, int n_in,
                              void* d_out, int out_size, void* d_ws, size_t ws_size,
                              hipStream_t stream) {
    const float* mean_t      = (const float*)d_in[0];
    const float* mean_s      = (const float*)d_in[1];
    const float* log_std_t   = (const float*)d_in[2];
    const float* log_std_s   = (const float*)d_in[3];
    const float* y_zt        = (const float*)d_in[4];
    const float* s_zt        = (const float*)d_in[5];
    const float* eps_prior_t = (const float*)d_in[6];
    const float* eps_prior_s = (const float*)d_in[7];
    const float* eps_t       = (const float*)d_in[8];
    const float* eps_s       = (const float*)d_in[9];
    const int*   target      = (const int*)d_in[10];
    const int*   step_ptr    = (const int*)d_in[11];

    double* ws_partial = (double*)d_ws;   // NBLK*3 doubles = 49 KiB
    float*  out        = (float*)d_out;

    crit_main<<<NBLK, 256, 0, stream>>>(
        mean_t, mean_s, log_std_t, log_std_s, y_zt, s_zt,
        eps_prior_t, eps_prior_s, eps_t, eps_s, target, ws_partial);
    crit_reduce<<<1, 256, 0, stream>>>(ws_partial, step_ptr, out);
}

// Round 5
// 239.203 us; speedup vs baseline: 1.1270x; 1.1270x over previous
//
#include <hip/hip_runtime.h>
#include <math.h>

// Problem constants (match reference)
#define BATCH 65536
#define NCLS  10
#define NBLK  2048              // 2048 blocks = exactly 8.0 rounds of 256 CUs
                                // each block: 4 waves x 8 KL rows = 32 KL rows
                                //             + 32 CE rows (lanes 0-7 of each wave)

// ws layout: ws[b*3+0]=ce, +1=H, +2=kl  -> 2048*3 doubles = 49 KiB

// Native clang vector type — __builtin_nontemporal_load rejects
// HIP_vector_type (float4) but accepts ext_vector_type.
typedef float vf4 __attribute__((ext_vector_type(4)));

// R11 evidence chain:
//  * R10 A/B isolated the nt hint: plain loads, SAME FETCH_SIZE (132.8 MB),
//    SAME occupancy, no spills -> dur DOUBLED (47.5 -> 102 us, 5.73 -> 2.67
//    TB/s delivered). gfx950 nt loads select a streaming path ~2x faster
//    for read-once data; plain loads pay L1/L2 allocation on every line.
//    This is the single biggest HW fact of the session: KEEP nt.
//  * R11 restores nt, keeps R10's even grid (2048 blocks = 8.0 exact
//    rounds, CE folded into lanes 0-7 of each wave) -> isolates the
//    ~3% grid-tail lever vs R7's 47.5 us.
//  * All other axes measured null: depth (R5/R7), occupancy 8->11 waves/CU
//    (R9, spill-corrected read), LLC residency (R4), VALU (R5).
//
// Numerics: max-subtraction omitted (N(0,1)-derived logits, extreme ~40,
// expf fine in fp32). R1-R10 absmax 0.0 vs 6e-2 threshold.

__global__ __launch_bounds__(256, 2) void crit_main(
    const float* __restrict__ mean_t,      const float* __restrict__ mean_s,
    const float* __restrict__ log_std_t,   const float* __restrict__ log_std_s,
    const float* __restrict__ y_zt,        const float* __restrict__ s_zt,
    const float* __restrict__ eps_prior_t, const float* __restrict__ eps_prior_s,
    const float* __restrict__ eps_t,       const float* __restrict__ eps_s,
    const int*   __restrict__ target,
    double*      __restrict__ ws_partial)
{
    const int tid = threadIdx.x;
    const int wid = tid >> 6;
    const int lane = tid & 63;

    // ---------------- KL phase: 16 lanes per row, 8 rows per wave ----------------
    const int sub  = lane & 15;          // lane within 16-lane group
    const int grp  = (lane >> 4) & 3;    // 4 groups = 4 rows per group-iter
    const int gwave = blockIdx.x * 4 + wid;
    const int rowbase = gwave * 8;       // 8 rows per wave (2 groups x 4)

    const vf4* MT = (const vf4*)mean_t;
    const vf4* LT = (const vf4*)log_std_t;
    const vf4* ET = (const vf4*)eps_t;
    const vf4* PT = (const vf4*)eps_prior_t;
    const vf4* MS = (const vf4*)mean_s;
    const vf4* LS = (const vf4*)log_std_s;
    const vf4* ES = (const vf4*)eps_s;
    const vf4* PS = (const vf4*)eps_prior_s;

    // vf4 indices for both row-groups
    int i0[2], i1[2];
    #pragma unroll
    for (int k = 0; k < 2; ++k) {
        const int row = rowbase + k * 4 + grp;
        i0[k] = row * 32 + sub;          // floats [sub*4 .. ) of the row
        i1[k] = i0[k] + 16;              // second half of the row
    }

    // ---- issue the stream loads (nontemporal: streaming path, 2x faster) ----
    vf4 mt[2][2], lt[2][2], et[2][2], pt[2][2];
    vf4 ms[2][2], ls[2][2], es[2][2], ps[2][2];
    #pragma unroll
    for (int k = 0; k < 2; ++k) {
        mt[k][0] = __builtin_nontemporal_load(&MT[i0[k]]);
        mt[k][1] = __builtin_nontemporal_load(&MT[i1[k]]);
        lt[k][0] = __builtin_nontemporal_load(&LT[i0[k]]);
        lt[k][1] = __builtin_nontemporal_load(&LT[i1[k]]);
        et[k][0] = __builtin_nontemporal_load(&ET[i0[k]]);
        et[k][1] = __builtin_nontemporal_load(&ET[i1[k]]);
        pt[k][0] = __builtin_nontemporal_load(&PT[i0[k]]);
        pt[k][1] = __builtin_nontemporal_load(&PT[i1[k]]);
        ms[k][0] = __builtin_nontemporal_load(&MS[i0[k]]);
        ms[k][1] = __builtin_nontemporal_load(&MS[i1[k]]);
        ls[k][0] = __builtin_nontemporal_load(&LS[i0[k]]);
        ls[k][1] = __builtin_nontemporal_load(&LS[i1[k]]);
        es[k][0] = __builtin_nontemporal_load(&ES[i0[k]]);
        es[k][1] = __builtin_nontemporal_load(&ES[i1[k]]);
        ps[k][0] = __builtin_nontemporal_load(&PS[i0[k]]);
        ps[k][1] = __builtin_nontemporal_load(&PS[i1[k]]);
    }
    // Scheduler fence: math may not be hoisted into the load clause.
    __builtin_amdgcn_sched_barrier(0);

    // ---- elementwise collapse: 6 partials per group ----
    // red[k]: 0=Ze_t 1=Zp_t 2=S_t 3=Ze_s 4=Zp_s 5=S_s
    float red[2][6];
    #pragma unroll
    for (int k = 0; k < 2; ++k) {
        #pragma unroll
        for (int j = 0; j < 6; ++j) red[k][j] = 0.0f;
        #pragma unroll
        for (int h = 0; h < 2; ++h) {
            #pragma unroll
            for (int c = 0; c < 4; ++c) {
                const float enc_t = fmaf(__expf(0.5f * lt[k][h][c]), et[k][h][c], mt[k][h][c]);
                const float enc_s = fmaf(__expf(0.5f * ls[k][h][c]), es[k][h][c], ms[k][h][c]);
                const float xt = __expf(enc_t);
                const float xs = __expf(enc_s);
                red[k][0] += xt;
                red[k][1] += __expf(pt[k][h][c]);
                red[k][2] += xt * (enc_t - pt[k][h][c]);
                red[k][3] += xs;
                red[k][4] += __expf(ps[k][h][c]);
                red[k][5] += xs * (enc_s - ps[k][h][c]);
            }
        }
    }

    // ---- joint butterfly: 4 levels x 12 values; each 16-lane group
    //      reduces its own row in the same instructions ----
    #pragma unroll
    for (int m = 8; m >= 1; m >>= 1) {
        #pragma unroll
        for (int k = 0; k < 2; ++k) {
            #pragma unroll
            for (int j = 0; j < 6; ++j) red[k][j] += __shfl_xor(red[k][j], m, 64);
        }
    }

    float kl = 0.0f;
    #pragma unroll
    for (int k = 0; k < 2; ++k) {
        const float rt = 1.0f / red[k][0];
        const float rs = 1.0f / red[k][3];
        kl += red[k][2] * rt + __logf(red[k][1] * rt)
            + red[k][5] * rs + __logf(red[k][4] * rs);
    }
    // Cross-group reduce (xor 16/32 only combine ACROSS the 4 groups,
    // each of which holds a group-uniform kl -> each row counted once).
    kl += __shfl_xor(kl, 16, 64);
    kl += __shfl_xor(kl, 32, 64);

    // ---------------- CE phase: lanes 0-7 of each wave take one row ----------------
    // Block covers CE rows [blockIdx.x*32, +32): wave wid, lane l<8 -> row +wid*8+l.
    double ce_d = 0.0, H_d = 0.0;
    if (lane < 8) {
        const int r = blockIdx.x * 32 + wid * 8 + lane;
        const float* yr = y_zt + (size_t)r * NCLS;
        const float2 y0 = *(const float2*)(yr + 0);
        const float2 y1 = *(const float2*)(yr + 2);
        const float2 y2 = *(const float2*)(yr + 4);
        const float2 y3 = *(const float2*)(yr + 6);
        const float2 y4 = *(const float2*)(yr + 8);
        const float2 s2 = *(const float2*)(s_zt + (size_t)r * 2);
        const int    t  = target[r];

        float yt = y0.x;
        yt = (t == 1) ? y0.y : yt;
        yt = (t == 2) ? y1.x : yt;
        yt = (t == 3) ? y1.y : yt;
        yt = (t == 4) ? y2.x : yt;
        yt = (t == 5) ? y2.y : yt;
        yt = (t == 6) ? y3.x : yt;
        yt = (t == 7) ? y3.y : yt;
        yt = (t == 8) ? y4.x : yt;
        yt = (t == 9) ? y4.y : yt;

        const float Z = (__expf(y0.x) + __expf(y0.y))
                      + (__expf(y1.x) + __expf(y1.y))
                      + (__expf(y2.x) + __expf(y2.y))
                      + (__expf(y3.x) + __expf(y3.y))
                      + (__expf(y4.x) + __expf(y4.y));
        ce_d = (double)(__logf(Z) - yt);

        const float za = __expf(s2.x), zb = __expf(s2.y);
        const float Zs = za + zb;
        const float lses = __logf(Zs);
        H_d = (double)(-((za / Zs) * (s2.x - lses) + (zb / Zs) * (s2.y - lses)));
    }
    // 3-level butterfly sums lanes 0-7 into lane 0 (xor m<=4 stays within
    // each 8-lane group; lanes >=8 hold zeros and sum among themselves).
    #pragma unroll
    for (int m = 4; m >= 1; m >>= 1) {
        ce_d += __shfl_xor(ce_d, m, 64);
        H_d  += __shfl_xor(H_d,  m, 64);
    }

    // ---------------- block epilogue: 1 barrier, 3 doubles out ----------------
    __shared__ double sred[4][3];
    if (lane == 0) {
        sred[wid][0] = ce_d;
        sred[wid][1] = H_d;
        sred[wid][2] = (double)kl;
    }
    __syncthreads();
    if (tid == 0) {
        ws_partial[blockIdx.x * 3 + 0] = sred[0][0] + sred[1][0] + sred[2][0] + sred[3][0];
        ws_partial[blockIdx.x * 3 + 1] = sred[0][1] + sred[1][1] + sred[2][1] + sred[3][1];
        ws_partial[blockIdx.x * 3 + 2] = sred[0][2] + sred[1][2] + sred[2][2] + sred[3][2];
    }
}

__global__ __launch_bounds__(256) void crit_reduce(
    const double* __restrict__ ws_partial,
    const int*    __restrict__ step_ptr,
    float*        __restrict__ out)
{
    const int tid = threadIdx.x;
    double c = 0.0, h = 0.0, k = 0.0;
    for (int i = tid; i < NBLK; i += 256) {
        c += ws_partial[3 * i + 0];
        h += ws_partial[3 * i + 1];
        k += ws_partial[3 * i + 2];
    }
    __shared__ double sc[256], sh_[256], sk[256];
    sc[tid] = c; sh_[tid] = h; sk[tid] = k;
    __syncthreads();
    for (int s = 128; s > 0; s >>= 1) {
        if (tid < s) { sc[tid] += sc[tid + s]; sh_[tid] += sh_[tid + s]; sk[tid] += sk[tid + s]; }
        __syncthreads();
    }
    if (tid == 0) {
        double frac  = (double)step_ptr[0] / 1000.0;   // STEP_SIZE
        double lam_e  = 0.1   * exp2(frac);            // LAMBDA_E * 2^frac
        double lam_od = 0.036 * exp2(frac);            // LAMBDA_OD * 2^frac
        out[0] = (float)((sc[0] + lam_e * sh_[0] + lam_od * sk[0]) / (double)BATCH);
    }
}

extern "C" void kernel_launch(void* const* d_in, const int* in_sizes, int n_in,
                              void* d_out, int out_size, void* d_ws, size_t ws_size,
                              hipStream_t stream) {
    const float* mean_t      = (const float*)d_in[0];
    const float* mean_s      = (const float*)d_in[1];
    const float* log_std_t   = (const float*)d_in[2];
    const float* log_std_s   = (const float*)d_in[3];
    const float* y_zt        = (const float*)d_in[4];
    const float* s_zt        = (const float*)d_in[5];
    const float* eps_prior_t = (const float*)d_in[6];
    const float* eps_prior_s = (const float*)d_in[7];
    const float* eps_t       = (const float*)d_in[8];
    const float* eps_s       = (const float*)d_in[9];
    const int*   target      = (const int*)d_in[10];
    const int*   step_ptr    = (const int*)d_in[11];

    double* ws_partial = (double*)d_ws;   // NBLK*3 doubles = 49 KiB
    float*  out        = (float*)d_out;

    crit_main<<<NBLK, 256, 0, stream>>>(
        mean_t, mean_s, log_std_t, log_std_s, y_zt, s_zt,
        eps_prior_t, eps_prior_s, eps_t, eps_s, target, ws_partial);
    crit_reduce<<<1, 256, 0, stream>>>(ws_partial, step_ptr, out);
}

// Round 6
// 237.416 us; speedup vs baseline: 1.1355x; 1.0075x over previous
//
#include <hip/hip_runtime.h>
#include <math.h>

// Problem constants (match reference)
#define BATCH 65536
#define NCLS  10
#define NBLK  2048              // 2048 blocks = exactly 8.0 rounds @ 2 blocks/CU
                                // each block: 4 waves x 8 KL rows = 32 KL rows
                                //             + 32 CE rows (8 per wave)

// ws layout: ws[b*3+0]=ce, +1=H, +2=kl  -> 2048*3 doubles = 49 KiB

// Native clang vector types — __builtin_nontemporal_load rejects
// HIP_vector_type but accepts ext_vector_type.
typedef float vf4 __attribute__((ext_vector_type(4)));
typedef float vf2 __attribute__((ext_vector_type(2)));

// R12 evidence chain:
//  * R10/R11 A/B: nt loads = 2x read throughput on gfx950 for read-once
//    streams (plain loads pay L1/L2 allocation; 102 vs 50.6 us). KEEP nt.
//  * R11 vs R7: CE folded AFTER the KL phase = +3.4 us (exposed ~900cy CE
//    load latency tail per wave x 4.0 rounds). The fold's serialization was
//    the regression, not the fold.
//  * R12: CE loads hoisted INTO the front load clause (overlap under the KL
//    drain), CE math at the end. Unconditional lane&7 loads (same lines,
//    no extra FETCH, no exec-mask); asm consume pins the 13 CE regs above
//    the math so IR sinking can't re-serialize them (R7 lesson).
//    Keeps the even grid: 2048 blocks = 8.0 exact rounds (R7 had 8.25).
//  * All other axes measured null: depth (R5/R7), occupancy (R9, spill-
//    corrected), LLC residency (R4), VALU (R5).
//
// Numerics: max-subtraction omitted (N(0,1)-derived logits, extreme ~40,
// expf fine in fp32). R1-R11 absmax 0.0 vs 6e-2 threshold.

__global__ __launch_bounds__(256, 2) void crit_main(
    const float* __restrict__ mean_t,      const float* __restrict__ mean_s,
    const float* __restrict__ log_std_t,   const float* __restrict__ log_std_s,
    const float* __restrict__ y_zt,        const float* __restrict__ s_zt,
    const float* __restrict__ eps_prior_t, const float* __restrict__ eps_prior_s,
    const float* __restrict__ eps_t,       const float* __restrict__ eps_s,
    const int*   __restrict__ target,
    double*      __restrict__ ws_partial)
{
    const int tid = threadIdx.x;
    const int wid = tid >> 6;
    const int lane = tid & 63;

    // ---------------- KL addressing: 16 lanes per row, 8 rows per wave ----------------
    const int sub  = lane & 15;          // lane within 16-lane group
    const int grp  = (lane >> 4) & 3;    // 4 groups = 4 rows per group-iter
    const int gwave = blockIdx.x * 4 + wid;
    const int rowbase = gwave * 8;       // 8 rows per wave (2 groups x 4)

    const vf4* MT = (const vf4*)mean_t;
    const vf4* LT = (const vf4*)log_std_t;
    const vf4* ET = (const vf4*)eps_t;
    const vf4* PT = (const vf4*)eps_prior_t;
    const vf4* MS = (const vf4*)mean_s;
    const vf4* LS = (const vf4*)log_std_s;
    const vf4* ES = (const vf4*)eps_s;
    const vf4* PS = (const vf4*)eps_prior_s;

    int i0[2], i1[2];
    #pragma unroll
    for (int k = 0; k < 2; ++k) {
        const int row = rowbase + k * 4 + grp;
        i0[k] = row * 32 + sub;          // floats [sub*4 .. ) of the row
        i1[k] = i0[k] + 16;              // second half of the row
    }

    // ---- front load clause: 32 KL stream loads (nt = streaming path) ----
    vf4 mt[2][2], lt[2][2], et[2][2], pt[2][2];
    vf4 ms[2][2], ls[2][2], es[2][2], ps[2][2];
    #pragma unroll
    for (int k = 0; k < 2; ++k) {
        mt[k][0] = __builtin_nontemporal_load(&MT[i0[k]]);
        mt[k][1] = __builtin_nontemporal_load(&MT[i1[k]]);
        lt[k][0] = __builtin_nontemporal_load(&LT[i0[k]]);
        lt[k][1] = __builtin_nontemporal_load(&LT[i1[k]]);
        et[k][0] = __builtin_nontemporal_load(&ET[i0[k]]);
        et[k][1] = __builtin_nontemporal_load(&ET[i1[k]]);
        pt[k][0] = __builtin_nontemporal_load(&PT[i0[k]]);
        pt[k][1] = __builtin_nontemporal_load(&PT[i1[k]]);
        ms[k][0] = __builtin_nontemporal_load(&MS[i0[k]]);
        ms[k][1] = __builtin_nontemporal_load(&MS[i1[k]]);
        ls[k][0] = __builtin_nontemporal_load(&LS[i0[k]]);
        ls[k][1] = __builtin_nontemporal_load(&LS[i1[k]]);
        es[k][0] = __builtin_nontemporal_load(&ES[i0[k]]);
        es[k][1] = __builtin_nontemporal_load(&ES[i1[k]]);
        ps[k][0] = __builtin_nontemporal_load(&PS[i0[k]]);
        ps[k][1] = __builtin_nontemporal_load(&PS[i1[k]]);
    }

    // ---- CE loads join the clause: unconditional, lane&7 row mapping ----
    // All 64 lanes read the same 8 rows -> identical cache lines, no extra
    // HBM fetch; avoids exec-masked loads. Accumulation is lane<8 only.
    const int cer = blockIdx.x * 32 + wid * 8 + (lane & 7);
    const vf2* Y2 = (const vf2*)(y_zt + (size_t)cer * NCLS);   // 40B rows, 8B aligned
    const vf2  y0 = __builtin_nontemporal_load(&Y2[0]);
    const vf2  y1 = __builtin_nontemporal_load(&Y2[1]);
    const vf2  y2 = __builtin_nontemporal_load(&Y2[2]);
    const vf2  y3 = __builtin_nontemporal_load(&Y2[3]);
    const vf2  y4 = __builtin_nontemporal_load(&Y2[4]);
    const vf2  s2 = __builtin_nontemporal_load((const vf2*)(s_zt + (size_t)cer * 2));
    const int  t  = __builtin_nontemporal_load(&target[cer]);

    // Scheduler fence: nothing may be hoisted into the load clause.
    __builtin_amdgcn_sched_barrier(0);
    // Pin ONLY the CE results live here: IR sinking would otherwise drag
    // these 7 loads down to their use after the KL math (the R11 tail).
    asm volatile("" ::
        "v"(y0), "v"(y1), "v"(y2), "v"(y3), "v"(y4), "v"(s2), "v"(t));

    // ---- KL elementwise collapse: 6 partials per group ----
    // red[k]: 0=Ze_t 1=Zp_t 2=S_t 3=Ze_s 4=Zp_s 5=S_s
    float red[2][6];
    #pragma unroll
    for (int k = 0; k < 2; ++k) {
        #pragma unroll
        for (int j = 0; j < 6; ++j) red[k][j] = 0.0f;
        #pragma unroll
        for (int h = 0; h < 2; ++h) {
            #pragma unroll
            for (int c = 0; c < 4; ++c) {
                const float enc_t = fmaf(__expf(0.5f * lt[k][h][c]), et[k][h][c], mt[k][h][c]);
                const float enc_s = fmaf(__expf(0.5f * ls[k][h][c]), es[k][h][c], ms[k][h][c]);
                const float xt = __expf(enc_t);
                const float xs = __expf(enc_s);
                red[k][0] += xt;
                red[k][1] += __expf(pt[k][h][c]);
                red[k][2] += xt * (enc_t - pt[k][h][c]);
                red[k][3] += xs;
                red[k][4] += __expf(ps[k][h][c]);
                red[k][5] += xs * (enc_s - ps[k][h][c]);
            }
        }
    }

    // ---- joint butterfly: 4 levels x 12 values ----
    #pragma unroll
    for (int m = 8; m >= 1; m >>= 1) {
        #pragma unroll
        for (int k = 0; k < 2; ++k) {
            #pragma unroll
            for (int j = 0; j < 6; ++j) red[k][j] += __shfl_xor(red[k][j], m, 64);
        }
    }

    float kl = 0.0f;
    #pragma unroll
    for (int k = 0; k < 2; ++k) {
        const float rt = 1.0f / red[k][0];
        const float rs = 1.0f / red[k][3];
        kl += red[k][2] * rt + __logf(red[k][1] * rt)
            + red[k][5] * rs + __logf(red[k][4] * rs);
    }
    // Cross-group reduce (xor 16/32 combine ACROSS the 4 groups).
    kl += __shfl_xor(kl, 16, 64);
    kl += __shfl_xor(kl, 32, 64);

    // ---- CE math from the long-resident regs; lane<8 accumulates ----
    double ce_d = 0.0, H_d = 0.0;
    {
        float yt = y0[0];
        yt = (t == 1) ? y0[1] : yt;
        yt = (t == 2) ? y1[0] : yt;
        yt = (t == 3) ? y1[1] : yt;
        yt = (t == 4) ? y2[0] : yt;
        yt = (t == 5) ? y2[1] : yt;
        yt = (t == 6) ? y3[0] : yt;
        yt = (t == 7) ? y3[1] : yt;
        yt = (t == 8) ? y4[0] : yt;
        yt = (t == 9) ? y4[1] : yt;

        const float Z = (__expf(y0[0]) + __expf(y0[1]))
                      + (__expf(y1[0]) + __expf(y1[1]))
                      + (__expf(y2[0]) + __expf(y2[1]))
                      + (__expf(y3[0]) + __expf(y3[1]))
                      + (__expf(y4[0]) + __expf(y4[1]));
        const float ce_f = __logf(Z) - yt;

        const float za = __expf(s2[0]), zb = __expf(s2[1]);
        const float Zs = za + zb;
        const float lses = __logf(Zs);
        const float H_f = -((za / Zs) * (s2[0] - lses) + (zb / Zs) * (s2[1] - lses));

        ce_d = (lane < 8) ? (double)ce_f : 0.0;
        H_d  = (lane < 8) ? (double)H_f  : 0.0;
    }
    // 3-level butterfly sums lanes 0-7 into lane 0.
    #pragma unroll
    for (int m = 4; m >= 1; m >>= 1) {
        ce_d += __shfl_xor(ce_d, m, 64);
        H_d  += __shfl_xor(H_d,  m, 64);
    }

    // ---------------- block epilogue: 1 barrier, 3 doubles out ----------------
    __shared__ double sred[4][3];
    if (lane == 0) {
        sred[wid][0] = ce_d;
        sred[wid][1] = H_d;
        sred[wid][2] = (double)kl;
    }
    __syncthreads();
    if (tid == 0) {
        ws_partial[blockIdx.x * 3 + 0] = sred[0][0] + sred[1][0] + sred[2][0] + sred[3][0];
        ws_partial[blockIdx.x * 3 + 1] = sred[0][1] + sred[1][1] + sred[2][1] + sred[3][1];
        ws_partial[blockIdx.x * 3 + 2] = sred[0][2] + sred[1][2] + sred[2][2] + sred[3][2];
    }
}

__global__ __launch_bounds__(256) void crit_reduce(
    const double* __restrict__ ws_partial,
    const int*    __restrict__ step_ptr,
    float*        __restrict__ out)
{
    const int tid = threadIdx.x;
    double c = 0.0, h = 0.0, k = 0.0;
    for (int i = tid; i < NBLK; i += 256) {
        c += ws_partial[3 * i + 0];
        h += ws_partial[3 * i + 1];
        k += ws_partial[3 * i + 2];
    }
    __shared__ double sc[256], sh_[256], sk[256];
    sc[tid] = c; sh_[tid] = h; sk[tid] = k;
    __syncthreads();
    for (int s = 128; s > 0; s >>= 1) {
        if (tid < s) { sc[tid] += sc[tid + s]; sh_[tid] += sh_[tid + s]; sk[tid] += sk[tid + s]; }
        __syncthreads();
    }
    if (tid == 0) {
        double frac  = (double)step_ptr[0] / 1000.0;   // STEP_SIZE
        double lam_e  = 0.1   * exp2(frac);            // LAMBDA_E * 2^frac
        double lam_od = 0.036 * exp2(frac);            // LAMBDA_OD * 2^frac
        out[0] = (float)((sc[0] + lam_e * sh_[0] + lam_od * sk[0]) / (double)BATCH);
    }
}

extern "C" void kernel_launch(void* const* d_in, const int* in_sizes, int n_in,
                              void* d_out, int out_size, void* d_ws, size_t ws_size,
                              hipStream_t stream) {
    const float* mean_t      = (const float*)d_in[0];
    const float* mean_s      = (const float*)d_in[1];
    const float* log_std_t   = (const float*)d_in[2];
    const float* log_std_s   = (const float*)d_in[3];
    const float* y_zt        = (const float*)d_in[4];
    const float* s_zt        = (const float*)d_in[5];
    const float* eps_prior_t = (const float*)d_in[6];
    const float* eps_prior_s = (const float*)d_in[7];
    const float* eps_t       = (const float*)d_in[8];
    const float* eps_s       = (const float*)d_in[9];
    const int*   target      = (const int*)d_in[10];
    const int*   step_ptr    = (const int*)d_in[11];

    double* ws_partial = (double*)d_ws;   // NBLK*3 doubles = 49 KiB
    float*  out        = (float*)d_out;

    crit_main<<<NBLK, 256, 0, stream>>>(
        mean_t, mean_s, log_std_t, log_std_s, y_zt, s_zt,
        eps_prior_t, eps_prior_s, eps_t, eps_s, target, ws_partial);
    crit_reduce<<<1, 256, 0, stream>>>(ws_partial, step_ptr, out);
}